// Round 16
// baseline (90.789 us; speedup 1.0000x reference)
//
#include <hip/hip_runtime.h>
#include <hip/hip_bf16.h>

#define B 4
#define S 2048
#define D 512
#define P 16
#define NC 64   // chunks over sequence
#define CL 32   // chunk length = S/NC

// ---------------------------------------------------------------------------
// Single fused kernel: prods+softmax -> chunk totals -> deterministic
// decoupled look-back prefix -> apply. Block = (b,c): c = blockIdx>>2,
// b = blockIdx&3 (predecessors of a chain sit at lower blockIdx). 512 thr.
// Co-residency guaranteed by cooperative launch; NO grid.sync is used.
// Look-back always sums predecessor AGGREGATES in ascending c order ->
// bit-identical to the old separate k_scan (deterministic, absmax 32.0).
// ---------------------------------------------------------------------------
__global__ __launch_bounds__(512) void k_fused(const float* __restrict__ x,
                                               const float* __restrict__ proxy,
                                               float* __restrict__ Tagg,
                                               int* __restrict__ flag,
                                               float* __restrict__ out) {
    __shared__ float s_pr[CL][P];
    __shared__ float s_w [CL][P];

    const int c    = blockIdx.x >> 2;
    const int b    = blockIdx.x & 3;
    const int tid  = threadIdx.x;
    const int lane = tid & 63;
    const int wv   = tid >> 6;          // 0..7
    const int bs0  = b * S + c * CL;

    // ---------------- Phase A: prods + softmax -> LDS (R15 body, no global)
    {
        float4 pA[P], pB[P];
#pragma unroll
        for (int p = 0; p < P; ++p) {
            const float* pr = proxy + p * D + lane * 8;
            pA[p] = *(const float4*)pr;
            pB[p] = *(const float4*)(pr + 4);
        }

#pragma unroll
        for (int r = 0; r < 4; ++r) {
            const int sl = wv * 4 + r;
            const int bs = bs0 + sl;
            const float* xr = x + (size_t)bs * D + lane * 8;
            float4 xa = *(const float4*)xr;
            float4 xb = *(const float4*)(xr + 4);

            float part[P];
#pragma unroll
            for (int p = 0; p < P; ++p) {
                part[p] = xa.x*pA[p].x + xa.y*pA[p].y + xa.z*pA[p].z + xa.w*pA[p].w
                        + xb.x*pB[p].x + xb.y*pB[p].y + xb.z*pB[p].z + xb.w*pB[p].w;
            }

            float a8[8];
#pragma unroll
            for (int k = 0; k < 8; ++k) {
                bool hi = lane & 1;
                float mine = hi ? part[2*k+1] : part[2*k];
                float oth  = hi ? part[2*k]   : part[2*k+1];
                a8[k] = mine + __shfl_xor(oth, 1);
            }
            float a4[4];
#pragma unroll
            for (int k = 0; k < 4; ++k) {
                bool hi = lane & 2;
                float mine = hi ? a8[2*k+1] : a8[2*k];
                float oth  = hi ? a8[2*k]   : a8[2*k+1];
                a4[k] = mine + __shfl_xor(oth, 2);
            }
            float a2[2];
#pragma unroll
            for (int k = 0; k < 2; ++k) {
                bool hi = lane & 4;
                float mine = hi ? a4[2*k+1] : a4[2*k];
                float oth  = hi ? a4[2*k]   : a4[2*k+1];
                a2[k] = mine + __shfl_xor(oth, 4);
            }
            float a1;
            {
                bool hi = lane & 8;
                float mine = hi ? a2[1] : a2[0];
                float oth  = hi ? a2[0] : a2[1];
                a1 = mine + __shfl_xor(oth, 8);
            }
            a1 += __shfl_xor(a1, 16);
            a1 += __shfl_xor(a1, 32);

            float m = a1;
#pragma unroll
            for (int off = 1; off < 16; off <<= 1) m = fmaxf(m, __shfl_xor(m, off));
            float e = __expf((a1 - m) * 0.25f);
            float den = e;
#pragma unroll
            for (int off = 1; off < 16; off <<= 1) den += __shfl_xor(den, off);

            if (lane < P) {
                s_pr[sl][lane] = a1;
                s_w [sl][lane] = e / den;
            }
        }
    }
    __syncthreads();

    // ---------------- Phase B: chunk totals (thread = d), publish aggregate
    const int d = tid;
    float xv[CL];
#pragma unroll
    for (int i = 0; i < CL; ++i) xv[i] = x[(size_t)(bs0 + i) * D + d];

    {
        float acc[P];
#pragma unroll
        for (int p = 0; p < P; ++p) acc[p] = 0.f;

#pragma unroll
        for (int i = 0; i < CL; ++i) {
            float pr[P];
            const float4* sp = (const float4*)&s_pr[i][0];
            ((float4*)pr)[0] = sp[0];
            ((float4*)pr)[1] = sp[1];
            ((float4*)pr)[2] = sp[2];
            ((float4*)pr)[3] = sp[3];
#pragma unroll
            for (int p = 0; p < P; ++p) acc[p] = fmaf(pr[p], xv[i], acc[p]);
        }
        size_t tb = ((size_t)(b * NC + c)) * (P * D) + d;
#pragma unroll
        for (int p = 0; p < P; ++p) Tagg[tb + p * D] = acc[p];
    }
    // barrier drains vmcnt -> all aggregate stores complete (in L2) before flag
    __syncthreads();
    if (tid == 0)
        __hip_atomic_store(&flag[blockIdx.x], 1, __ATOMIC_RELEASE,
                           __HIP_MEMORY_SCOPE_AGENT);

    // ---------------- Look-back: exclusive prefix, ascending c (bit-stable)
    float st[P];
#pragma unroll
    for (int p = 0; p < P; ++p) st[p] = 0.f;

    if (c > 0) {
        // thread cc (< c) spin-waits on predecessor (b, cc)'s flag
        if (tid < c) {
            while (__hip_atomic_load(&flag[(tid << 2) | b], __ATOMIC_RELAXED,
                                     __HIP_MEMORY_SCOPE_AGENT) == 0)
                __builtin_amdgcn_s_sleep(2);
        }
        __syncthreads();
        // one acquire per thread: orders + invalidates caches for payload reads
        (void)__hip_atomic_load(&flag[((c - 1) << 2) | b], __ATOMIC_ACQUIRE,
                                __HIP_MEMORY_SCOPE_AGENT);

#pragma unroll 4
        for (int cc = 0; cc < c; ++cc) {
            size_t ta = ((size_t)(b * NC + cc)) * (P * D) + d;
#pragma unroll
            for (int p = 0; p < P; ++p) st[p] += Tagg[ta + p * D];
        }
    }

    // ---------------- Phase C: apply (R13 body; xv still live in VGPRs)
#pragma unroll
    for (int i = 0; i < CL; ++i) {
        float pr[P], ww[P];
        const float4* sp = (const float4*)&s_pr[i][0];
        const float4* sw = (const float4*)&s_w [i][0];
        ((float4*)pr)[0] = sp[0];
        ((float4*)pr)[1] = sp[1];
        ((float4*)pr)[2] = sp[2];
        ((float4*)pr)[3] = sp[3];
        ((float4*)ww)[0] = sw[0];
        ((float4*)ww)[1] = sw[1];
        ((float4*)ww)[2] = sw[2];
        ((float4*)ww)[3] = sw[3];
        float o = 0.f;
#pragma unroll
        for (int p = 0; p < P; ++p) {
            st[p] = fmaf(pr[p], xv[i], st[p]);
            o = fmaf(ww[p], st[p], o);
        }
        out[(size_t)(bs0 + i) * D + d] = o;
    }
}

extern "C" void kernel_launch(void* const* d_in, const int* in_sizes, int n_in,
                              void* d_out, int out_size, void* d_ws, size_t ws_size,
                              hipStream_t stream) {
    const float* x     = (const float*)d_in[0];
    const float* proxy = (const float*)d_in[1];
    float* out  = (float*)d_out;

    float* Tagg = (float*)d_ws;                              // 8 MiB
    int*   flags = (int*)((char*)d_ws +
                          (size_t)B * NC * P * D * sizeof(float));

    hipMemsetAsync(flags, 0, (B * NC) * sizeof(int), stream);

    void* args[] = { (void*)&x, (void*)&proxy, (void*)&Tagg,
                     (void*)&flags, (void*)&out };
    hipLaunchCooperativeKernel((void*)k_fused, dim3(B * NC), dim3(512),
                               args, 0, stream);
}

// Round 17
// 34.848 us; speedup vs baseline: 2.6053x; 2.6053x over previous
//
#include <hip/hip_runtime.h>
#include <hip/hip_bf16.h>

#define B 4
#define S 2048
#define D 512
#define P 16
#define NC 64   // chunks over sequence
#define CL 32   // chunk length = S/NC

// ---------------------------------------------------------------------------
// Kernel 1: prods + softmax (R10/R13 verbatim). One wave per 4 rows, proxy
// hoisted to VGPRs, merge-tree reduction.
// ---------------------------------------------------------------------------
__global__ __launch_bounds__(256) void k_prods(const float* __restrict__ x,
                                               const float* __restrict__ proxy,
                                               float* __restrict__ prods,
                                               float* __restrict__ wgt) {
    const int wave = (blockIdx.x * blockDim.x + threadIdx.x) >> 6;  // 0..2047
    const int lane = threadIdx.x & 63;
    const int bs0  = wave * 4;

    float4 pA[P], pB[P];
#pragma unroll
    for (int p = 0; p < P; ++p) {
        const float* pr = proxy + p * D + lane * 8;
        pA[p] = *(const float4*)pr;
        pB[p] = *(const float4*)(pr + 4);
    }

#pragma unroll
    for (int r = 0; r < 4; ++r) {
        const int bs = bs0 + r;
        const float* xr = x + (size_t)bs * D + lane * 8;
        float4 xa = *(const float4*)xr;
        float4 xb = *(const float4*)(xr + 4);

        float part[P];
#pragma unroll
        for (int p = 0; p < P; ++p) {
            part[p] = xa.x*pA[p].x + xa.y*pA[p].y + xa.z*pA[p].z + xa.w*pA[p].w
                    + xb.x*pB[p].x + xb.y*pB[p].y + xb.z*pB[p].z + xb.w*pB[p].w;
        }

        float a8[8];
#pragma unroll
        for (int k = 0; k < 8; ++k) {
            bool hi = lane & 1;
            float mine = hi ? part[2*k+1] : part[2*k];
            float oth  = hi ? part[2*k]   : part[2*k+1];
            a8[k] = mine + __shfl_xor(oth, 1);
        }
        float a4[4];
#pragma unroll
        for (int k = 0; k < 4; ++k) {
            bool hi = lane & 2;
            float mine = hi ? a8[2*k+1] : a8[2*k];
            float oth  = hi ? a8[2*k]   : a8[2*k+1];
            a4[k] = mine + __shfl_xor(oth, 2);
        }
        float a2[2];
#pragma unroll
        for (int k = 0; k < 2; ++k) {
            bool hi = lane & 4;
            float mine = hi ? a4[2*k+1] : a4[2*k];
            float oth  = hi ? a4[2*k]   : a4[2*k+1];
            a2[k] = mine + __shfl_xor(oth, 4);
        }
        float a1;
        {
            bool hi = lane & 8;
            float mine = hi ? a2[1] : a2[0];
            float oth  = hi ? a2[0] : a2[1];
            a1 = mine + __shfl_xor(oth, 8);
        }
        a1 += __shfl_xor(a1, 16);
        a1 += __shfl_xor(a1, 32);

        float m = a1;
#pragma unroll
        for (int off = 1; off < 16; off <<= 1) m = fmaxf(m, __shfl_xor(m, off));
        float e = __expf((a1 - m) * 0.25f);
        float den = e;
#pragma unroll
        for (int off = 1; off < 16; off <<= 1) den += __shfl_xor(den, off);

        if (lane < P) {
            prods[(size_t)bs * P + lane] = a1;
            wgt  [(size_t)bs * P + lane] = e / den;
        }
    }
}

// ---------------------------------------------------------------------------
// Kernel 2: chunk totals T[b,c,p,d] (R13 verbatim). Block = (b,c,half).
// ---------------------------------------------------------------------------
__global__ __launch_bounds__(256) void k_totals(const float* __restrict__ x,
                                                const float* __restrict__ prods,
                                                float* __restrict__ T) {
    int h = blockIdx.x & 1;
    int c = (blockIdx.x >> 1) & (NC - 1);
    int b = blockIdx.x >> 7;
    int d = h * 256 + threadIdx.x;

    float acc[P];
#pragma unroll
    for (int p = 0; p < P; ++p) acc[p] = 0.f;

    int bs0 = b * S + c * CL;
#pragma unroll 4
    for (int i = 0; i < CL; ++i) {
        int bs = bs0 + i;
        float xv = x[(size_t)bs * D + d];
        const float4* pp = (const float4*)(prods + (size_t)bs * P);
        float pr[P];
        ((float4*)pr)[0] = pp[0];
        ((float4*)pr)[1] = pp[1];
        ((float4*)pr)[2] = pp[2];
        ((float4*)pr)[3] = pp[3];
#pragma unroll
        for (int p = 0; p < P; ++p) acc[p] = fmaf(pr[p], xv, acc[p]);
    }
    size_t tb = ((size_t)(b * NC + c)) * (P * D) + d;
#pragma unroll
    for (int p = 0; p < P; ++p) T[tb + p * D] = acc[p];
}

// ---------------------------------------------------------------------------
// Kernel 3: segmented exclusive prefix over 64 chunks (R12-proven design).
// 512 blocks x 256 thr; block = (b, p, dgrp of 64); thread = (dl, seg g of 4).
// Each thread: 16 independent loads -> register prefix; segment totals cross
// via LDS. Grid 512 (was 128 — half the CUs idle) and chain depth 16 (was 64).
// ---------------------------------------------------------------------------
__global__ __launch_bounds__(256) void k_scan(float* __restrict__ T) {
    __shared__ float s_tot[4][64];

    const int dgrp = blockIdx.x & 7;
    const int p    = (blockIdx.x >> 3) & 15;
    const int b    = blockIdx.x >> 7;
    const int dl   = threadIdx.x & 63;
    const int g    = threadIdx.x >> 6;          // segment 0..3
    const int d    = dgrp * 64 + dl;

    const size_t chunk_stride = (size_t)P * D;
    const size_t base = ((size_t)b * NC * P + p) * D + d
                      + (size_t)(g * 16) * chunk_stride;

    float v[16];
#pragma unroll
    for (int c = 0; c < 16; ++c) v[c] = T[base + (size_t)c * chunk_stride];

    float tot = 0.f;
#pragma unroll
    for (int c = 0; c < 16; ++c) tot += v[c];

    s_tot[g][dl] = tot;
    __syncthreads();

    float run = 0.f;
#pragma unroll
    for (int gg = 0; gg < 3; ++gg)
        if (gg < g) run += s_tot[gg][dl];

#pragma unroll
    for (int c = 0; c < 16; ++c) {
        T[base + (size_t)c * chunk_stride] = run;
        run += v[c];
    }
}

// ---------------------------------------------------------------------------
// Kernel 4: apply (R13 body + o split into 4 accumulators to cut the
// 16-deep dependent FMA chain to 4). Block = (b,c,half), 256 threads.
// ---------------------------------------------------------------------------
__global__ __launch_bounds__(256) void k_apply(const float* __restrict__ x,
                                               const float* __restrict__ prods,
                                               const float* __restrict__ wgt,
                                               const float* __restrict__ T,
                                               float* __restrict__ out) {
    __shared__ float s_pw[2][CL][P];    // [0]=prods, [1]=wgt : 4 KiB

    int h = blockIdx.x & 1;
    int c = (blockIdx.x >> 1) & (NC - 1);
    int b = blockIdx.x >> 7;
    int d = h * 256 + threadIdx.x;
    int bs0 = b * S + c * CL;

    {
        int t = threadIdx.x;
        if (t < 128) {
            ((float4*)&s_pw[0][0][0])[t] =
                ((const float4*)(prods + (size_t)bs0 * P))[t];
        } else {
            ((float4*)&s_pw[1][0][0])[t - 128] =
                ((const float4*)(wgt + (size_t)bs0 * P))[t - 128];
        }
    }

    float xv[CL];
#pragma unroll
    for (int i = 0; i < CL; ++i) xv[i] = x[(size_t)(bs0 + i) * D + d];

    float st[P];
    size_t tb = ((size_t)(b * NC + c)) * (P * D) + d;
#pragma unroll
    for (int p = 0; p < P; ++p) st[p] = T[tb + p * D];

    __syncthreads();

#pragma unroll
    for (int i = 0; i < CL; ++i) {
        float pr[P], ww[P];
        const float4* sp = (const float4*)&s_pw[0][i][0];
        const float4* sw = (const float4*)&s_pw[1][i][0];
        ((float4*)pr)[0] = sp[0];
        ((float4*)pr)[1] = sp[1];
        ((float4*)pr)[2] = sp[2];
        ((float4*)pr)[3] = sp[3];
        ((float4*)ww)[0] = sw[0];
        ((float4*)ww)[1] = sw[1];
        ((float4*)ww)[2] = sw[2];
        ((float4*)ww)[3] = sw[3];
        float o0 = 0.f, o1 = 0.f, o2 = 0.f, o3 = 0.f;
#pragma unroll
        for (int p = 0; p < P; p += 4) {
            st[p+0] = fmaf(pr[p+0], xv[i], st[p+0]);
            o0 = fmaf(ww[p+0], st[p+0], o0);
            st[p+1] = fmaf(pr[p+1], xv[i], st[p+1]);
            o1 = fmaf(ww[p+1], st[p+1], o1);
            st[p+2] = fmaf(pr[p+2], xv[i], st[p+2]);
            o2 = fmaf(ww[p+2], st[p+2], o2);
            st[p+3] = fmaf(pr[p+3], xv[i], st[p+3]);
            o3 = fmaf(ww[p+3], st[p+3], o3);
        }
        out[(size_t)(bs0 + i) * D + d] = (o0 + o1) + (o2 + o3);
    }
}

extern "C" void kernel_launch(void* const* d_in, const int* in_sizes, int n_in,
                              void* d_out, int out_size, void* d_ws, size_t ws_size,
                              hipStream_t stream) {
    const float* x     = (const float*)d_in[0];
    const float* proxy = (const float*)d_in[1];
    float* out   = (float*)d_out;

    float* prods = (float*)d_ws;                 // 512 KiB
    float* wgt   = prods + (size_t)B * S * P;    // 512 KiB
    float* T     = wgt   + (size_t)B * S * P;    // 8 MiB

    k_prods <<<(B * S) / 16, 256, 0, stream>>>(x, proxy, prods, wgt);
    k_totals<<<B * NC * 2,   256, 0, stream>>>(x, prods, T);
    k_scan  <<<B * P * 8,    256, 0, stream>>>(T);
    k_apply <<<B * NC * 2,   256, 0, stream>>>(x, prods, wgt, T, out);
}

// Round 18
// 34.585 us; speedup vs baseline: 2.6251x; 1.0076x over previous
//
#include <hip/hip_runtime.h>
#include <hip/hip_bf16.h>

#define B 4
#define S 2048
#define D 512
#define P 16
#define NC 64   // chunks over sequence
#define CL 32   // chunk length = S/NC

// ---------------------------------------------------------------------------
// Kernel 1: prods + softmax. One wave per 4 rows, proxy hoisted to VGPRs.
// R18 change: ALL 4 rows' x loads issued up-front (8 independent float4s in
// flight) so rows 1-3's loads complete under row 0's shuffle chain.
// Per-row arithmetic (FMA order, merge-tree, softmax) is R17-verbatim.
// ---------------------------------------------------------------------------
__global__ __launch_bounds__(256) void k_prods(const float* __restrict__ x,
                                               const float* __restrict__ proxy,
                                               float* __restrict__ prods,
                                               float* __restrict__ wgt) {
    const int wave = (blockIdx.x * blockDim.x + threadIdx.x) >> 6;  // 0..2047
    const int lane = threadIdx.x & 63;
    const int bs0  = wave * 4;

    // issue x loads for all 4 rows first (8 loads in flight)
    float4 xa[4], xb[4];
#pragma unroll
    for (int r = 0; r < 4; ++r) {
        const float* xr = x + (size_t)(bs0 + r) * D + lane * 8;
        xa[r] = *(const float4*)xr;
        xb[r] = *(const float4*)(xr + 4);
    }

    // proxy slices (L1-hot after first waves)
    float4 pA[P], pB[P];
#pragma unroll
    for (int p = 0; p < P; ++p) {
        const float* pr = proxy + p * D + lane * 8;
        pA[p] = *(const float4*)pr;
        pB[p] = *(const float4*)(pr + 4);
    }

#pragma unroll
    for (int r = 0; r < 4; ++r) {
        const int bs = bs0 + r;

        float part[P];
#pragma unroll
        for (int p = 0; p < P; ++p) {
            part[p] = xa[r].x*pA[p].x + xa[r].y*pA[p].y + xa[r].z*pA[p].z + xa[r].w*pA[p].w
                    + xb[r].x*pB[p].x + xb[r].y*pB[p].y + xb[r].z*pB[p].z + xb[r].w*pB[p].w;
        }

        float a8[8];
#pragma unroll
        for (int k = 0; k < 8; ++k) {
            bool hi = lane & 1;
            float mine = hi ? part[2*k+1] : part[2*k];
            float oth  = hi ? part[2*k]   : part[2*k+1];
            a8[k] = mine + __shfl_xor(oth, 1);
        }
        float a4[4];
#pragma unroll
        for (int k = 0; k < 4; ++k) {
            bool hi = lane & 2;
            float mine = hi ? a8[2*k+1] : a8[2*k];
            float oth  = hi ? a8[2*k]   : a8[2*k+1];
            a4[k] = mine + __shfl_xor(oth, 2);
        }
        float a2[2];
#pragma unroll
        for (int k = 0; k < 2; ++k) {
            bool hi = lane & 4;
            float mine = hi ? a4[2*k+1] : a4[2*k];
            float oth  = hi ? a4[2*k]   : a4[2*k+1];
            a2[k] = mine + __shfl_xor(oth, 4);
        }
        float a1;
        {
            bool hi = lane & 8;
            float mine = hi ? a2[1] : a2[0];
            float oth  = hi ? a2[0] : a2[1];
            a1 = mine + __shfl_xor(oth, 8);
        }
        a1 += __shfl_xor(a1, 16);
        a1 += __shfl_xor(a1, 32);

        float m = a1;
#pragma unroll
        for (int off = 1; off < 16; off <<= 1) m = fmaxf(m, __shfl_xor(m, off));
        float e = __expf((a1 - m) * 0.25f);
        float den = e;
#pragma unroll
        for (int off = 1; off < 16; off <<= 1) den += __shfl_xor(den, off);

        if (lane < P) {
            prods[(size_t)bs * P + lane] = a1;
            wgt  [(size_t)bs * P + lane] = e / den;
        }
    }
}

// ---------------------------------------------------------------------------
// Kernel 2: chunk totals T[b,c,p,d] (R17 verbatim). Block = (b,c,half).
// ---------------------------------------------------------------------------
__global__ __launch_bounds__(256) void k_totals(const float* __restrict__ x,
                                                const float* __restrict__ prods,
                                                float* __restrict__ T) {
    int h = blockIdx.x & 1;
    int c = (blockIdx.x >> 1) & (NC - 1);
    int b = blockIdx.x >> 7;
    int d = h * 256 + threadIdx.x;

    float acc[P];
#pragma unroll
    for (int p = 0; p < P; ++p) acc[p] = 0.f;

    int bs0 = b * S + c * CL;
#pragma unroll 4
    for (int i = 0; i < CL; ++i) {
        int bs = bs0 + i;
        float xv = x[(size_t)bs * D + d];
        const float4* pp = (const float4*)(prods + (size_t)bs * P);
        float pr[P];
        ((float4*)pr)[0] = pp[0];
        ((float4*)pr)[1] = pp[1];
        ((float4*)pr)[2] = pp[2];
        ((float4*)pr)[3] = pp[3];
#pragma unroll
        for (int p = 0; p < P; ++p) acc[p] = fmaf(pr[p], xv, acc[p]);
    }
    size_t tb = ((size_t)(b * NC + c)) * (P * D) + d;
#pragma unroll
    for (int p = 0; p < P; ++p) T[tb + p * D] = acc[p];
}

// ---------------------------------------------------------------------------
// Kernel 3: segmented exclusive prefix (R17 verbatim). 512 blocks x 256 thr.
// ---------------------------------------------------------------------------
__global__ __launch_bounds__(256) void k_scan(float* __restrict__ T) {
    __shared__ float s_tot[4][64];

    const int dgrp = blockIdx.x & 7;
    const int p    = (blockIdx.x >> 3) & 15;
    const int b    = blockIdx.x >> 7;
    const int dl   = threadIdx.x & 63;
    const int g    = threadIdx.x >> 6;          // segment 0..3
    const int d    = dgrp * 64 + dl;

    const size_t chunk_stride = (size_t)P * D;
    const size_t base = ((size_t)b * NC * P + p) * D + d
                      + (size_t)(g * 16) * chunk_stride;

    float v[16];
#pragma unroll
    for (int c = 0; c < 16; ++c) v[c] = T[base + (size_t)c * chunk_stride];

    float tot = 0.f;
#pragma unroll
    for (int c = 0; c < 16; ++c) tot += v[c];

    s_tot[g][dl] = tot;
    __syncthreads();

    float run = 0.f;
#pragma unroll
    for (int gg = 0; gg < 3; ++gg)
        if (gg < g) run += s_tot[gg][dl];

#pragma unroll
    for (int c = 0; c < 16; ++c) {
        T[base + (size_t)c * chunk_stride] = run;
        run += v[c];
    }
}

// ---------------------------------------------------------------------------
// Kernel 4: apply (R17 verbatim: LDS-staged weights, xv preload, o-split).
// ---------------------------------------------------------------------------
__global__ __launch_bounds__(256) void k_apply(const float* __restrict__ x,
                                               const float* __restrict__ prods,
                                               const float* __restrict__ wgt,
                                               const float* __restrict__ T,
                                               float* __restrict__ out) {
    __shared__ float s_pw[2][CL][P];    // [0]=prods, [1]=wgt : 4 KiB

    int h = blockIdx.x & 1;
    int c = (blockIdx.x >> 1) & (NC - 1);
    int b = blockIdx.x >> 7;
    int d = h * 256 + threadIdx.x;
    int bs0 = b * S + c * CL;

    {
        int t = threadIdx.x;
        if (t < 128) {
            ((float4*)&s_pw[0][0][0])[t] =
                ((const float4*)(prods + (size_t)bs0 * P))[t];
        } else {
            ((float4*)&s_pw[1][0][0])[t - 128] =
                ((const float4*)(wgt + (size_t)bs0 * P))[t - 128];
        }
    }

    float xv[CL];
#pragma unroll
    for (int i = 0; i < CL; ++i) xv[i] = x[(size_t)(bs0 + i) * D + d];

    float st[P];
    size_t tb = ((size_t)(b * NC + c)) * (P * D) + d;
#pragma unroll
    for (int p = 0; p < P; ++p) st[p] = T[tb + p * D];

    __syncthreads();

#pragma unroll
    for (int i = 0; i < CL; ++i) {
        float pr[P], ww[P];
        const float4* sp = (const float4*)&s_pw[0][i][0];
        const float4* sw = (const float4*)&s_pw[1][i][0];
        ((float4*)pr)[0] = sp[0];
        ((float4*)pr)[1] = sp[1];
        ((float4*)pr)[2] = sp[2];
        ((float4*)pr)[3] = sp[3];
        ((float4*)ww)[0] = sw[0];
        ((float4*)ww)[1] = sw[1];
        ((float4*)ww)[2] = sw[2];
        ((float4*)ww)[3] = sw[3];
        float o0 = 0.f, o1 = 0.f, o2 = 0.f, o3 = 0.f;
#pragma unroll
        for (int p = 0; p < P; p += 4) {
            st[p+0] = fmaf(pr[p+0], xv[i], st[p+0]);
            o0 = fmaf(ww[p+0], st[p+0], o0);
            st[p+1] = fmaf(pr[p+1], xv[i], st[p+1]);
            o1 = fmaf(ww[p+1], st[p+1], o1);
            st[p+2] = fmaf(pr[p+2], xv[i], st[p+2]);
            o2 = fmaf(ww[p+2], st[p+2], o2);
            st[p+3] = fmaf(pr[p+3], xv[i], st[p+3]);
            o3 = fmaf(ww[p+3], st[p+3], o3);
        }
        out[(size_t)(bs0 + i) * D + d] = (o0 + o1) + (o2 + o3);
    }
}

extern "C" void kernel_launch(void* const* d_in, const int* in_sizes, int n_in,
                              void* d_out, int out_size, void* d_ws, size_t ws_size,
                              hipStream_t stream) {
    const float* x     = (const float*)d_in[0];
    const float* proxy = (const float*)d_in[1];
    float* out   = (float*)d_out;

    float* prods = (float*)d_ws;                 // 512 KiB
    float* wgt   = prods + (size_t)B * S * P;    // 512 KiB
    float* T     = wgt   + (size_t)B * S * P;    // 8 MiB

    k_prods <<<(B * S) / 16, 256, 0, stream>>>(x, proxy, prods, wgt);
    k_totals<<<B * NC * 2,   256, 0, stream>>>(x, prods, T);
    k_scan  <<<B * P * 8,    256, 0, stream>>>(T);
    k_apply <<<B * NC * 2,   256, 0, stream>>>(x, prods, wgt, T, out);
}